// Round 7
// baseline (113.907 us; speedup 1.0000x reference)
//
#include <hip/hip_runtime.h>
#include <hip/hip_bf16.h>

// Problem constants (from reference)
#define BS    4
#define CH    64
#define HH    32
#define WW    88
#define NZ    60
#define BEV_Z 10
#define BEV_X 128
#define BEV_Y 128

static constexpr int HW        = HH * WW;        // 2816
static constexpr int ZX        = BEV_Z * BEV_X;  // 1280
static constexpr int PTS_PER_B = NZ * HW;        // 168960

static constexpr int T            = 16;              // hw columns per count tile
static constexpr int NT           = HW / T;          // 176 tiles per batch
static constexpr int CNT_BLOCKS   = BS * NT;         // 704
static constexpr int NXELEM       = BS * CH * HW;    // 720896
static constexpr int XCONV_BLOCKS = NXELEM / 4096;   // 176
static constexpr int CNT_WORDS    = ZX * T / 4;      // 5120 u32 words (20 KB tile)
static constexpr int TILE_BYTES   = ZX * T;          // 20480
static constexpr int ZGROUPS      = ZX / 64;         // 20

typedef __attribute__((ext_vector_type(8))) short short8;   // bf16x8 MFMA frag
typedef __attribute__((ext_vector_type(4))) float floatx4;  // fp32x4 acc

__device__ inline unsigned short f2b(float v) {
    __hip_bfloat16 h = __float2bfloat16(v);
    return *reinterpret_cast<unsigned short*>(&h);
}

// u8 count (exact int <=60) -> bf16 bits: cvt to f32 (exact), take top 16
__device__ inline short cnt2bf(unsigned int w, int s) {
    float fv = (float)((w >> s) & 255u);
    unsigned int u;
    __builtin_memcpy(&u, &fv, 4);
    return (short)(u >> 16);
}

// ---- K1: blocks 0..703 build u8 count tiles (tile-major, coalesced dump);
//          blocks 704..879 cast x fp32 -> bf16 ----
__global__ __launch_bounds__(256)
void build_kernel(const float* __restrict__ x, const int* __restrict__ f,
                  unsigned int* __restrict__ cnt8,
                  unsigned short* __restrict__ xbf) {
    __shared__ unsigned int cnt[CNT_WORDS];   // [zx][hw_l] u8-packed, 20 KB
    int blk = blockIdx.x;
    if (blk < CNT_BLOCKS) {
        int b   = blk / NT;
        int t   = blk % NT;
        int hw0 = t * T;
        for (int i = threadIdx.x; i < CNT_WORDS; i += 256) cnt[i] = 0u;
        __syncthreads();

        int hw_l = threadIdx.x & 15;
        int z0   = threadIdx.x >> 4;          // 16 z-rows per pass
        for (int z = z0; z < NZ; z += 16) {
            int p  = b * PTS_PER_B + z * HW + hw0 + hw_l;
            int xx = f[3 * p + 0];
            int yy = f[3 * p + 1];
            int zz = f[3 * p + 2];
            bool kept = (xx >= 0) & (xx < BEV_X) & (yy >= 0) & (yy < BEV_Y) &
                        (zz >= 0) & (zz < BEV_Z);
            if (kept) {
                int cell = (zz * BEV_X + xx) * T + hw_l;   // counts <= 60
                atomicAdd(&cnt[cell >> 2], 1u << (8 * (cell & 3)));
            }
        }
        __syncthreads();

        // contiguous 20 KB dump: cnt8[b][t][zx*16+hw_l] u8 == word-for-word LDS
        unsigned int* obase = cnt8 + (size_t)(b * NT + t) * CNT_WORDS;
        for (int i = threadIdx.x; i < CNT_WORDS; i += 256) obase[i] = cnt[i];
    } else {
        // cast x (b,ch,hw) fp32 -> bf16, same layout
        size_t base = (size_t)(blk - CNT_BLOCKS) * 4096;
        #pragma unroll
        for (int r = 0; r < 4; ++r) {
            size_t i = base + ((size_t)r * 256 + threadIdx.x) * 4;
            floatx4 v = *(const floatx4*)(x + i);
            ushort4 o;
            o.x = f2b(v.x); o.y = f2b(v.y); o.z = f2b(v.z); o.w = f2b(v.w);
            *(ushort4*)(xbf + i) = o;
        }
    }
}

// ---- K2: out[b] (64ch x 1280zx) = xbf[b] (64x2816) * cnt[b]^T (2816x1280) ----
// Block = (b, 64-zx group); wave = 16-zx tile; loop over 4 ch-tiles internally
// so the B (count) fragment is loaded ONCE and reused by 4 MFMA.
// B[k][n]: lane holds n=lane&15 (zx), k=quad*8+j. With tile-major u8 storage:
//   addr = b_base + (k0/16 + (quad>>1))*TILE_BYTES + zx*16 + (quad&1)*8
// A[m][k]: lane holds m=lane&15 (ch), k=quad*8+j -> 16B contiguous in hw.
// D: col(zx)=lane&15, row(ch)=quad*4+reg  [verified in R6]
__global__ __launch_bounds__(256)
void gemm_kernel(const unsigned short* __restrict__ xbf,
                 const unsigned char* __restrict__ cnt8,
                 float* __restrict__ out) {
    int blk  = blockIdx.x;                 // 0..79
    int b    = blk / ZGROUPS;
    int zg   = blk % ZGROUPS;
    int wave = threadIdx.x >> 6;
    int lane = threadIdx.x & 63;
    int m    = lane & 15;
    int quad = lane >> 4;
    int zx   = zg * 64 + wave * 16 + m;

    const unsigned char* pb = cnt8 + (size_t)b * NT * TILE_BYTES
                            + (size_t)(quad >> 1) * TILE_BYTES
                            + zx * T + (quad & 1) * 8;
    const unsigned short* pa = xbf + ((size_t)(b * CH) + m) * HW + quad * 8;

    floatx4 acc0 = {0.f,0.f,0.f,0.f}, acc1 = {0.f,0.f,0.f,0.f};
    floatx4 acc2 = {0.f,0.f,0.f,0.f}, acc3 = {0.f,0.f,0.f,0.f};

    for (int k0 = 0; k0 < HW; k0 += 32) {
        uint2 wv = *(const uint2*)pb;      // 8 u8 counts, k = k0+quad*8 .. +7
        pb += 2 * TILE_BYTES;
        short8 bf;
        bf[0] = cnt2bf(wv.x,  0); bf[1] = cnt2bf(wv.x,  8);
        bf[2] = cnt2bf(wv.x, 16); bf[3] = cnt2bf(wv.x, 24);
        bf[4] = cnt2bf(wv.y,  0); bf[5] = cnt2bf(wv.y,  8);
        bf[6] = cnt2bf(wv.y, 16); bf[7] = cnt2bf(wv.y, 24);

        short8 a0 = *(const short8*)(pa + 0 * 16 * HW + k0);
        short8 a1 = *(const short8*)(pa + 1 * 16 * HW + k0);
        short8 a2 = *(const short8*)(pa + 2 * 16 * HW + k0);
        short8 a3 = *(const short8*)(pa + 3 * 16 * HW + k0);

        acc0 = __builtin_amdgcn_mfma_f32_16x16x32_bf16(a0, bf, acc0, 0, 0, 0);
        acc1 = __builtin_amdgcn_mfma_f32_16x16x32_bf16(a1, bf, acc1, 0, 0, 0);
        acc2 = __builtin_amdgcn_mfma_f32_16x16x32_bf16(a2, bf, acc2, 0, 0, 0);
        acc3 = __builtin_amdgcn_mfma_f32_16x16x32_bf16(a3, bf, acc3, 0, 0, 0);
    }

    float* ob = out + (size_t)b * CH * ZX + zx;
    #pragma unroll
    for (int r = 0; r < 4; ++r) {
        int ch = quad * 4 + r;
        ob[(0 * 16 + ch) * ZX] = acc0[r];
        ob[(1 * 16 + ch) * ZX] = acc1[r];
        ob[(2 * 16 + ch) * ZX] = acc2[r];
        ob[(3 * 16 + ch) * ZX] = acc3[r];
    }
}

extern "C" void kernel_launch(void* const* d_in, const int* in_sizes, int n_in,
                              void* d_out, int out_size, void* d_ws, size_t ws_size,
                              hipStream_t stream) {
    const float* x = (const float*)d_in[0];
    const int*   f = (const int*)d_in[1];
    float*       out = (float*)d_out;

    char* ws = (char*)d_ws;
    size_t off = 0;
    auto carve = [&](size_t bytes) {
        char* p = ws + off;
        off += (bytes + 255) & ~(size_t)255;
        return p;
    };
    unsigned int*   cnt8 = (unsigned int*)  carve((size_t)BS * NT * TILE_BYTES); // 14.4 MB
    unsigned short* xbf  = (unsigned short*)carve((size_t)NXELEM * 2);           // 1.44 MB
    // both fully written by K1 before K2 reads them -> no memset needed

    build_kernel<<<CNT_BLOCKS + XCONV_BLOCKS, 256, 0, stream>>>(x, f, cnt8, xbf);
    gemm_kernel <<<BS * ZGROUPS, 256, 0, stream>>>(xbf, (const unsigned char*)cnt8, out);
}

// Round 8
// 90.753 us; speedup vs baseline: 1.2551x; 1.2551x over previous
//
#include <hip/hip_runtime.h>
#include <hip/hip_bf16.h>

// Problem constants (from reference)
#define BS    4
#define CH    64
#define HH    32
#define WW    88
#define NZ    60
#define BEV_Z 10
#define BEV_X 128
#define BEV_Y 128

static constexpr int HW        = HH * WW;        // 2816
static constexpr int ZX        = BEV_Z * BEV_X;  // 1280
static constexpr int PTS_PER_B = NZ * HW;        // 168960

static constexpr int T            = 16;              // hw columns per count tile
static constexpr int NT           = HW / T;          // 176 tiles per batch
static constexpr int CNT_BLOCKS   = BS * NT;         // 704
static constexpr int NXELEM       = BS * CH * HW;    // 720896
static constexpr int XCONV_BLOCKS = NXELEM / 4096;   // 176
static constexpr int CNT_WORDS    = ZX * T / 4;      // 5120 u32 words (20 KB tile)
static constexpr int TILE_BYTES   = ZX * T;          // 20480
static constexpr int ZGROUPS      = ZX / 64;         // 20

static constexpr int KS     = 11;                    // K-split chunks
static constexpr int KCH    = HW / KS;               // 256 hw per chunk
static constexpr int OUTSZ  = BS * CH * ZX;          // 327680

typedef __attribute__((ext_vector_type(8))) short short8;   // bf16x8 MFMA frag
typedef __attribute__((ext_vector_type(4))) float floatx4;  // fp32x4 acc

__device__ inline unsigned short f2b(float v) {
    __hip_bfloat16 h = __float2bfloat16(v);
    return *reinterpret_cast<unsigned short*>(&h);
}

// u8 count (exact int <=60) -> bf16 bits: cvt to f32 (exact), take top 16
__device__ inline short cnt2bf(unsigned int w, int s) {
    float fv = (float)((w >> s) & 255u);
    unsigned int u;
    __builtin_memcpy(&u, &fv, 4);
    return (short)(u >> 16);
}

// ---- K1: blocks 0..703 build u8 count tiles (tile-major, coalesced dump);
//          blocks 704..879 cast x fp32 -> bf16 ----
__global__ __launch_bounds__(256)
void build_kernel(const float* __restrict__ x, const int* __restrict__ f,
                  unsigned int* __restrict__ cnt8,
                  unsigned short* __restrict__ xbf) {
    __shared__ unsigned int cnt[CNT_WORDS];   // [zx][hw_l] u8-packed, 20 KB
    int blk = blockIdx.x;
    if (blk < CNT_BLOCKS) {
        int b   = blk / NT;
        int t   = blk % NT;
        int hw0 = t * T;
        for (int i = threadIdx.x; i < CNT_WORDS; i += 256) cnt[i] = 0u;
        __syncthreads();

        int hw_l = threadIdx.x & 15;
        int z0   = threadIdx.x >> 4;          // 16 z-rows per pass
        for (int z = z0; z < NZ; z += 16) {
            int p  = b * PTS_PER_B + z * HW + hw0 + hw_l;
            int xx = f[3 * p + 0];
            int yy = f[3 * p + 1];
            int zz = f[3 * p + 2];
            bool kept = (xx >= 0) & (xx < BEV_X) & (yy >= 0) & (yy < BEV_Y) &
                        (zz >= 0) & (zz < BEV_Z);
            if (kept) {
                int cell = (zz * BEV_X + xx) * T + hw_l;   // counts <= 60
                atomicAdd(&cnt[cell >> 2], 1u << (8 * (cell & 3)));
            }
        }
        __syncthreads();

        // contiguous 20 KB dump: cnt8[b][t][zx*16+hw_l] u8 == word-for-word LDS
        unsigned int* obase = cnt8 + (size_t)(b * NT + t) * CNT_WORDS;
        for (int i = threadIdx.x; i < CNT_WORDS; i += 256) obase[i] = cnt[i];
    } else {
        // cast x (b,ch,hw) fp32 -> bf16, same layout
        size_t base = (size_t)(blk - CNT_BLOCKS) * 4096;
        #pragma unroll
        for (int r = 0; r < 4; ++r) {
            size_t i = base + ((size_t)r * 256 + threadIdx.x) * 4;
            floatx4 v = *(const floatx4*)(x + i);
            ushort4 o;
            o.x = f2b(v.x); o.y = f2b(v.y); o.z = f2b(v.z); o.w = f2b(v.w);
            *(ushort4*)(xbf + i) = o;
        }
    }
}

// ---- K2: K-split GEMM. Block = (b, 64-zx group, K-chunk); 8 iters/block.
// Partials P[kc][b][ch][zx] fp32. Fragment layouts as verified in R6/R7.
__global__ __launch_bounds__(256)
void gemm_kernel(const unsigned short* __restrict__ xbf,
                 const unsigned char* __restrict__ cnt8,
                 float* __restrict__ P) {
    int blk  = blockIdx.x;                 // 0..879
    int kc   = blk % KS;
    int r2   = blk / KS;
    int b    = r2 / ZGROUPS;
    int zg   = r2 % ZGROUPS;
    int wave = threadIdx.x >> 6;
    int lane = threadIdx.x & 63;
    int m    = lane & 15;
    int quad = lane >> 4;
    int zx   = zg * 64 + wave * 16 + m;
    int k0   = kc * KCH;

    const unsigned char* pb = cnt8 + (size_t)b * NT * TILE_BYTES
                            + (size_t)(k0 / T + (quad >> 1)) * TILE_BYTES
                            + zx * T + (quad & 1) * 8;
    const unsigned short* pa = xbf + ((size_t)(b * CH) + m) * HW + k0 + quad * 8;

    floatx4 acc0 = {0.f,0.f,0.f,0.f}, acc1 = {0.f,0.f,0.f,0.f};
    floatx4 acc2 = {0.f,0.f,0.f,0.f}, acc3 = {0.f,0.f,0.f,0.f};

    #pragma unroll 2
    for (int kk = 0; kk < KCH; kk += 32) {
        uint2 wv = *(const uint2*)pb;      // 8 u8 counts, k = k0+kk+quad*8..+7
        pb += 2 * TILE_BYTES;
        short8 bf;
        bf[0] = cnt2bf(wv.x,  0); bf[1] = cnt2bf(wv.x,  8);
        bf[2] = cnt2bf(wv.x, 16); bf[3] = cnt2bf(wv.x, 24);
        bf[4] = cnt2bf(wv.y,  0); bf[5] = cnt2bf(wv.y,  8);
        bf[6] = cnt2bf(wv.y, 16); bf[7] = cnt2bf(wv.y, 24);

        short8 a0 = *(const short8*)(pa + 0 * 16 * HW + kk);
        short8 a1 = *(const short8*)(pa + 1 * 16 * HW + kk);
        short8 a2 = *(const short8*)(pa + 2 * 16 * HW + kk);
        short8 a3 = *(const short8*)(pa + 3 * 16 * HW + kk);

        acc0 = __builtin_amdgcn_mfma_f32_16x16x32_bf16(a0, bf, acc0, 0, 0, 0);
        acc1 = __builtin_amdgcn_mfma_f32_16x16x32_bf16(a1, bf, acc1, 0, 0, 0);
        acc2 = __builtin_amdgcn_mfma_f32_16x16x32_bf16(a2, bf, acc2, 0, 0, 0);
        acc3 = __builtin_amdgcn_mfma_f32_16x16x32_bf16(a3, bf, acc3, 0, 0, 0);
    }

    float* op = P + ((size_t)(kc * BS + b) * CH) * ZX + zx;
    #pragma unroll
    for (int r = 0; r < 4; ++r) {
        int ch = quad * 4 + r;
        op[(0 * 16 + ch) * ZX] = acc0[r];
        op[(1 * 16 + ch) * ZX] = acc1[r];
        op[(2 * 16 + ch) * ZX] = acc2[r];
        op[(3 * 16 + ch) * ZX] = acc3[r];
    }
}

// ---- K3: out = sum over 11 K-chunk partials, fully coalesced ----
__global__ __launch_bounds__(256)
void reduce_kernel(const float* __restrict__ P, float* __restrict__ out) {
    int idx = blockIdx.x * 256 + threadIdx.x;    // 0..OUTSZ-1
    float s = 0.f;
    #pragma unroll
    for (int kc = 0; kc < KS; ++kc)
        s += P[(size_t)kc * OUTSZ + idx];
    out[idx] = s;
}

extern "C" void kernel_launch(void* const* d_in, const int* in_sizes, int n_in,
                              void* d_out, int out_size, void* d_ws, size_t ws_size,
                              hipStream_t stream) {
    const float* x = (const float*)d_in[0];
    const int*   f = (const int*)d_in[1];
    float*       out = (float*)d_out;

    char* ws = (char*)d_ws;
    size_t off = 0;
    auto carve = [&](size_t bytes) {
        char* p = ws + off;
        off += (bytes + 255) & ~(size_t)255;
        return p;
    };
    unsigned int*   cnt8 = (unsigned int*)  carve((size_t)BS * NT * TILE_BYTES); // 14.4 MB
    unsigned short* xbf  = (unsigned short*)carve((size_t)NXELEM * 2);           // 1.44 MB
    float*          P    = (float*)         carve((size_t)KS * OUTSZ * 4);       // 14.4 MB
    // all fully written before being read -> no memsets needed

    build_kernel <<<CNT_BLOCKS + XCONV_BLOCKS, 256, 0, stream>>>(x, f, cnt8, xbf);
    gemm_kernel  <<<BS * ZGROUPS * KS, 256, 0, stream>>>(xbf, (const unsigned char*)cnt8, P);
    reduce_kernel<<<OUTSZ / 256, 256, 0, stream>>>(P, out);
}

// Round 9
// 88.103 us; speedup vs baseline: 1.2929x; 1.0301x over previous
//
#include <hip/hip_runtime.h>
#include <hip/hip_bf16.h>

// Problem constants (from reference)
#define BS    4
#define CH    64
#define HH    32
#define WW    88
#define NZ    60
#define BEV_Z 10
#define BEV_X 128
#define BEV_Y 128

static constexpr int HW        = HH * WW;        // 2816
static constexpr int ZX        = BEV_Z * BEV_X;  // 1280
static constexpr int PTS_PER_B = NZ * HW;        // 168960

static constexpr int T            = 16;              // hw columns per count tile
static constexpr int NT           = HW / T;          // 176 tiles per batch
static constexpr int CNT_BLOCKS   = BS * NT;         // 704
static constexpr int NXELEM       = BS * CH * HW;    // 720896
static constexpr int XCONV_BLOCKS = NXELEM / 4096;   // 176
static constexpr int CNT_WORDS    = ZX * T / 4;      // 5120 u32 words (20 KB tile)
static constexpr int TILE_BYTES   = ZX * T;          // 20480
static constexpr int ZGROUPS      = ZX / 64;         // 20

static constexpr int KS     = 11;                    // K-split chunks
static constexpr int KCH    = HW / KS;               // 256 hw per chunk
static constexpr int OUTSZ  = BS * CH * ZX;          // 327680

static constexpr int BPTS   = NZ * T;                // 960 points per count block
static constexpr int FSLAB4 = BPTS * 3 / 4;          // 720 uint4 (11.5 KB)

typedef __attribute__((ext_vector_type(8))) short short8;   // bf16x8 MFMA frag
typedef __attribute__((ext_vector_type(4))) float floatx4;  // fp32x4 acc

__device__ inline unsigned short f2b(float v) {
    __hip_bfloat16 h = __float2bfloat16(v);
    return *reinterpret_cast<unsigned short*>(&h);
}

// u8 count (exact int <=60) -> bf16 bits: cvt to f32 (exact), take top 16
__device__ inline short cnt2bf(unsigned int w, int s) {
    float fv = (float)((w >> s) & 255u);
    unsigned int u;
    __builtin_memcpy(&u, &fv, 4);
    return (short)(u >> 16);
}

__device__ inline float bfbits2f(unsigned int bits) {   // bits already in [31:16]
    float fv;
    __builtin_memcpy(&fv, &bits, 4);
    return fv;
}

// ---- K1: blocks 0..703 build u8 count tiles (tile-major, coalesced dump);
//          blocks 704..879 cast x fp32 -> bf16 ----
__global__ __launch_bounds__(256)
void build_kernel(const float* __restrict__ x, const int* __restrict__ f,
                  unsigned int* __restrict__ cnt8,
                  unsigned short* __restrict__ xbf) {
    __shared__ unsigned int cnt[CNT_WORDS];   // [zx][hw_l] u8-packed, 20 KB
    __shared__ uint4 fslab[FSLAB4];           // staged frustum slab, 11.5 KB
    int blk = blockIdx.x;
    if (blk < CNT_BLOCKS) {
        int b   = blk / NT;
        int t   = blk % NT;
        int hw0 = t * T;
        for (int i = threadIdx.x; i < CNT_WORDS; i += 256) cnt[i] = 0u;

        // stage f for this block's 960 points: 60 z-segments x 192 B,
        // each segment = 12 uint4, fully coalesced 16B loads
        int p0 = b * PTS_PER_B + hw0;                    // multiple of 16
        const uint4* fb = (const uint4*)(f + (size_t)p0 * 3);
        constexpr int SEG4 = HW * 3 / 4;                 // uint4 stride per z (2112)
        for (int i = threadIdx.x; i < FSLAB4; i += 256) {
            int z = i / 12, w16 = i % 12;
            fslab[i] = fb[(size_t)z * SEG4 + w16];
        }
        __syncthreads();

        const unsigned int* fs = (const unsigned int*)fslab;
        #pragma unroll
        for (int r = 0; r < 4; ++r) {
            int j = r * 256 + threadIdx.x;               // point idx in block
            if (j < BPTS) {
                int xx = (int)fs[j * 3 + 0];
                int yy = (int)fs[j * 3 + 1];
                int zz = (int)fs[j * 3 + 2];
                bool kept = (xx >= 0) & (xx < BEV_X) & (yy >= 0) & (yy < BEV_Y) &
                            (zz >= 0) & (zz < BEV_Z);
                if (kept) {
                    int hw_l = j & 15;                   // j = z*16 + hw_l
                    int cell = (zz * BEV_X + xx) * T + hw_l;   // counts <= 60
                    atomicAdd(&cnt[cell >> 2], 1u << (8 * (cell & 3)));
                }
            }
        }
        __syncthreads();

        // contiguous 20 KB dump: cnt8[b][t][zx*16+hw_l] u8 == word-for-word LDS
        unsigned int* obase = cnt8 + (size_t)(b * NT + t) * CNT_WORDS;
        for (int i = threadIdx.x; i < CNT_WORDS; i += 256) obase[i] = cnt[i];
    } else {
        // cast x (b,ch,hw) fp32 -> bf16, same layout
        size_t base = (size_t)(blk - CNT_BLOCKS) * 4096;
        #pragma unroll
        for (int r = 0; r < 4; ++r) {
            size_t i = base + ((size_t)r * 256 + threadIdx.x) * 4;
            floatx4 v = *(const floatx4*)(x + i);
            ushort4 o;
            o.x = f2b(v.x); o.y = f2b(v.y); o.z = f2b(v.z); o.w = f2b(v.w);
            *(ushort4*)(xbf + i) = o;
        }
    }
}

// ---- K2: K-split GEMM. Block = (b, 64-zx group, K-chunk); 8 iters/block.
// Partials P[kc][b][ch][zx] in bf16. Fragment layouts as verified in R6-R8.
__global__ __launch_bounds__(256)
void gemm_kernel(const unsigned short* __restrict__ xbf,
                 const unsigned char* __restrict__ cnt8,
                 unsigned short* __restrict__ P) {
    int blk  = blockIdx.x;                 // 0..879
    int kc   = blk % KS;
    int r2   = blk / KS;
    int b    = r2 / ZGROUPS;
    int zg   = r2 % ZGROUPS;
    int wave = threadIdx.x >> 6;
    int lane = threadIdx.x & 63;
    int m    = lane & 15;
    int quad = lane >> 4;
    int zx   = zg * 64 + wave * 16 + m;
    int k0   = kc * KCH;

    const unsigned char* pb = cnt8 + (size_t)b * NT * TILE_BYTES
                            + (size_t)(k0 / T + (quad >> 1)) * TILE_BYTES
                            + zx * T + (quad & 1) * 8;
    const unsigned short* pa = xbf + ((size_t)(b * CH) + m) * HW + k0 + quad * 8;

    floatx4 acc0 = {0.f,0.f,0.f,0.f}, acc1 = {0.f,0.f,0.f,0.f};
    floatx4 acc2 = {0.f,0.f,0.f,0.f}, acc3 = {0.f,0.f,0.f,0.f};

    #pragma unroll 4
    for (int kk = 0; kk < KCH; kk += 32) {
        uint2 wv = *(const uint2*)pb;      // 8 u8 counts, k = k0+kk+quad*8..+7
        pb += 2 * TILE_BYTES;
        short8 bf;
        bf[0] = cnt2bf(wv.x,  0); bf[1] = cnt2bf(wv.x,  8);
        bf[2] = cnt2bf(wv.x, 16); bf[3] = cnt2bf(wv.x, 24);
        bf[4] = cnt2bf(wv.y,  0); bf[5] = cnt2bf(wv.y,  8);
        bf[6] = cnt2bf(wv.y, 16); bf[7] = cnt2bf(wv.y, 24);

        short8 a0 = *(const short8*)(pa + 0 * 16 * HW + kk);
        short8 a1 = *(const short8*)(pa + 1 * 16 * HW + kk);
        short8 a2 = *(const short8*)(pa + 2 * 16 * HW + kk);
        short8 a3 = *(const short8*)(pa + 3 * 16 * HW + kk);

        acc0 = __builtin_amdgcn_mfma_f32_16x16x32_bf16(a0, bf, acc0, 0, 0, 0);
        acc1 = __builtin_amdgcn_mfma_f32_16x16x32_bf16(a1, bf, acc1, 0, 0, 0);
        acc2 = __builtin_amdgcn_mfma_f32_16x16x32_bf16(a2, bf, acc2, 0, 0, 0);
        acc3 = __builtin_amdgcn_mfma_f32_16x16x32_bf16(a3, bf, acc3, 0, 0, 0);
    }

    unsigned short* op = P + ((size_t)(kc * BS + b) * CH) * ZX + zx;
    #pragma unroll
    for (int r = 0; r < 4; ++r) {
        int ch = quad * 4 + r;
        op[(0 * 16 + ch) * ZX] = f2b(acc0[r]);
        op[(1 * 16 + ch) * ZX] = f2b(acc1[r]);
        op[(2 * 16 + ch) * ZX] = f2b(acc2[r]);
        op[(3 * 16 + ch) * ZX] = f2b(acc3[r]);
    }
}

// ---- K3: out = sum of 11 bf16 K-chunk partials; 2 outputs per thread ----
__global__ __launch_bounds__(256)
void reduce_kernel(const unsigned int* __restrict__ P, float* __restrict__ out) {
    int idx = blockIdx.x * 256 + threadIdx.x;    // 0..OUTSZ/2-1, pair index
    float s_lo = 0.f, s_hi = 0.f;
    #pragma unroll
    for (int kc = 0; kc < KS; ++kc) {
        unsigned int u = P[(size_t)kc * (OUTSZ / 2) + idx];
        s_lo += bfbits2f(u << 16);
        s_hi += bfbits2f(u & 0xFFFF0000u);
    }
    *(float2*)(out + (size_t)idx * 2) = make_float2(s_lo, s_hi);
}

extern "C" void kernel_launch(void* const* d_in, const int* in_sizes, int n_in,
                              void* d_out, int out_size, void* d_ws, size_t ws_size,
                              hipStream_t stream) {
    const float* x = (const float*)d_in[0];
    const int*   f = (const int*)d_in[1];
    float*       out = (float*)d_out;

    char* ws = (char*)d_ws;
    size_t off = 0;
    auto carve = [&](size_t bytes) {
        char* p = ws + off;
        off += (bytes + 255) & ~(size_t)255;
        return p;
    };
    unsigned int*   cnt8 = (unsigned int*)  carve((size_t)BS * NT * TILE_BYTES); // 14.4 MB
    unsigned short* xbf  = (unsigned short*)carve((size_t)NXELEM * 2);           // 1.44 MB
    unsigned short* P    = (unsigned short*)carve((size_t)KS * OUTSZ * 2);       // 7.2 MB
    // all fully written before being read -> no memsets needed

    build_kernel <<<CNT_BLOCKS + XCONV_BLOCKS, 256, 0, stream>>>(x, f, cnt8, xbf);
    gemm_kernel  <<<BS * ZGROUPS * KS, 256, 0, stream>>>(xbf, (const unsigned char*)cnt8, P);
    reduce_kernel<<<OUTSZ / 2 / 256, 256, 0, stream>>>((const unsigned int*)P, out);
}